// Round 6
// baseline (124.530 us; speedup 1.0000x reference)
//
#include <hip/hip_runtime.h>
#include <stdint.h>

// ColBERT MaxSim on MI355X (gfx950), round 12.
// scores[b,c] = sum_n max_s dot(qs[b,n,:], ps[c,s,:])
// qs: (64, 32, 128) f32, ps: (64, 1024, 128) f32, out: (64, 64) f32.
//
// R11 post-mortem: the 256 MiB d_ws poison fill (~43 us) is UNCONDITIONAL --
// it reappeared in top-5 with d_ws untouched; R10's "conditional" read was
// the fills sitting just under the top-5 cutoff. Budget accounting across
// R10/R11: dur = fill 43 + cvt 8 + maxsim + gaps ~22 => R11 maxsim ~= 38 us
// (vs 13.7 us MFMA wall).
//
// R12 (one variable): delete cvt_kernel by fusing f32->bf16 into maxsim's
// staging. gload_lds can't convert, so P-staging becomes reg-transit:
// global f32 loads (issued at tile start, latency hides under the 16 MFMAs)
// -> v_cvt_pk_bf16_f32 -> ds_write_b128 into the back buffer just before
// the barrier (T14 async-STAGE split). LDS layout, traffic, barrier
// structure, grid (512x256), and 2-queries/wave qf residency are all
// UNCHANGED from R11. Q loads f32 directly in the prologue. g_bf deleted.
// Peak live regs ~= 64 qf + 32 acc + 16 F + ~15 misc ~= 130 (benign 3-wave
// allocator zone; R8's fatal demand was 236).
// Predict: dur 111.5 -> ~99-103 (-8 us cvt, -1-3 us launch gap); top-5 still
// all ~43 us fills. FAILURE signal: maxsim in top-5 (>42 us) => reg-staging
// re-triggered qf demotion => revert to R11.

typedef __bf16 bf16x8 __attribute__((ext_vector_type(8)));
typedef float floatx16 __attribute__((ext_vector_type(16)));

__device__ inline bf16x8 cvt8(const float4& a, const float4& b) {
  bf16x8 r;
  r[0] = (__bf16)a.x; r[1] = (__bf16)a.y; r[2] = (__bf16)a.z; r[3] = (__bf16)a.w;
  r[4] = (__bf16)b.x; r[5] = (__bf16)b.y; r[6] = (__bf16)b.z; r[7] = (__bf16)b.w;
  return r;
}

__device__ inline float rmax16(const floatx16& a) {
  // Nested fmaxf triples fuse to v_max3_f32.
  float m0 = fmaxf(fmaxf(a[0], a[1]), fmaxf(a[2], a[3]));
  float m1 = fmaxf(fmaxf(a[4], a[5]), fmaxf(a[6], a[7]));
  float m2 = fmaxf(fmaxf(a[8], a[9]), fmaxf(a[10], a[11]));
  float m3 = fmaxf(fmaxf(a[12], a[13]), fmaxf(a[14], a[15]));
  return fmaxf(fmaxf(m0, m1), fmaxf(m2, m3));
}

#define ZERO16 {0, 0, 0, 0, 0, 0, 0, 0, 0, 0, 0, 0, 0, 0, 0, 0}

__global__ __launch_bounds__(256) void maxsim_kernel(const float* __restrict__ qs,
                                                     const float* __restrict__ ps,
                                                     float* __restrict__ out) {
  const int lane = threadIdx.x & 63;
  const int wave = threadIdx.x >> 6;

  // XCD swizzle: the 8 blocks of doc c all land on XCD c>>3 -> P_c (512 KB
  // f32) L2-resident after the first reader.
  const int xcd = blockIdx.x & 7;
  const int slot = blockIdx.x >> 3;   // 0..63
  const int c = xcd * 8 + (slot >> 3);
  const int bg = slot & 7;
  const int qb0 = bg * 8 + wave * 2;  // this wave's first query (of 2)

  const int row = lane & 31;          // A-frag: s-row; B-frag: query token n
  const int hi8 = (lane >> 5) * 8;    // K-half selector (elements)

  // Q B-frags f32 global -> cvt -> reg, resident all kernel (64 VGPRs):
  // qf[bb][k] = Q[qb0+bb][n=row][k*16 + hi8 + 0..7] as bf16.
  bf16x8 qf[2][8];
#pragma unroll
  for (int bb = 0; bb < 2; ++bb) {
    const float* q = qs + ((qb0 + bb) * 32 + row) * 128 + hi8;
#pragma unroll
    for (int k = 0; k < 8; ++k) {
      float4 a = *(const float4*)(q + k * 16);
      float4 b = *(const float4*)(q + k * 16 + 4);
      qf[bb][k] = cvt8(a, b);
    }
  }

  // P tile double-buffer (bf16, 8 KB each), A-frag order: chunk j at
  // j*1024 B, lane at *16 B. Content: lds[j*512 + t*8..] =
  // P[c][s0 + (t&31)][j*16 + (t>>5)*8 ..] -- identical layout to R11.
  __shared__ __align__(16) ushort lds_p[2][4096];

  // Per-lane f32 global base (add s0*128 + j*16 per chunk).
  const float* pg = ps + (c * 1024 + row) * 128 + hi8;

  // Prologue: stage tile 0 (wave w owns chunks 2w, 2w+1).
#pragma unroll
  for (int jj = 0; jj < 2; ++jj) {
    const int j = wave * 2 + jj;
    const float* src = pg + j * 16;
    float4 a = *(const float4*)src;
    float4 b = *(const float4*)(src + 4);
    *(bf16x8*)(&lds_p[0][j * 512 + lane * 8]) = cvt8(a, b);
  }
  __syncthreads();

  float vmax0 = -3.4e38f, vmax1 = -3.4e38f;
  int cb = 0;

#pragma unroll 1
  for (int t = 0; t < 32; ++t) {
    // Issue next tile's f32 loads NOW (L2 latency hides under the MFMAs).
    float4 Fa0, Fb0, Fa1, Fb1;
    if (t < 31) {
      const float* src = pg + (t + 1) * 32 * 128 + (wave * 2) * 16;
      Fa0 = *(const float4*)src;
      Fb0 = *(const float4*)(src + 4);
      Fa1 = *(const float4*)(src + 16);
      Fb1 = *(const float4*)(src + 20);
    }
    // Compute tile t: one contiguous ds_read_b128 feeds both queries' MFMAs.
    const ushort* lp = &lds_p[cb][0] + lane * 8;
    floatx16 acc0 = ZERO16, acc1 = ZERO16;
#pragma unroll
    for (int k = 0; k < 8; ++k) {
      bf16x8 af = *(const bf16x8*)(lp + k * 512);
      acc0 = __builtin_amdgcn_mfma_f32_32x32x16_bf16(af, qf[0][k], acc0, 0, 0, 0);
      acc1 = __builtin_amdgcn_mfma_f32_32x32x16_bf16(af, qf[1][k], acc1, 0, 0, 0);
    }
    vmax0 = fmaxf(vmax0, rmax16(acc0));
    vmax1 = fmaxf(vmax1, rmax16(acc1));
    // Write staged data into the back buffer (cvt_pk + ds_write_b128 x2),
    // then barrier: writes land AND all readers of cb are done.
    if (t < 31) {
      ushort* dst = &lds_p[cb ^ 1][(wave * 2) * 512 + lane * 8];
      *(bf16x8*)dst = cvt8(Fa0, Fb0);
      *(bf16x8*)(dst + 512) = cvt8(Fa1, Fb1);
    }
    __syncthreads();
    cb ^= 1;
  }

  // acc D-layout: col = lane&31 = token n; lanes l, l^32 hold complementary
  // row-halves -> max-merge, then butterfly-sum the 32 tokens.
  vmax0 = fmaxf(vmax0, __shfl_xor(vmax0, 32, 64));
  vmax1 = fmaxf(vmax1, __shfl_xor(vmax1, 32, 64));
#pragma unroll
  for (int o = 16; o > 0; o >>= 1) {
    vmax0 += __shfl_xor(vmax0, o, 64);
    vmax1 += __shfl_xor(vmax1, o, 64);
  }
  if (lane == 0) {
    out[(qb0 + 0) * 64 + c] = vmax0;
    out[(qb0 + 1) * 64 + c] = vmax1;
  }
}

extern "C" void kernel_launch(void* const* d_in, const int* in_sizes, int n_in,
                              void* d_out, int out_size, void* d_ws, size_t ws_size,
                              hipStream_t stream) {
  const float* qs = (const float*)d_in[0];
  const float* ps = (const float*)d_in[1];
  float* out = (float*)d_out;
  (void)d_ws; (void)ws_size;  // ws poison fill is unconditional; ws gives us nothing

  maxsim_kernel<<<dim3(512), dim3(256), 0, stream>>>(qs, ps, out);
}

// Round 7
// 111.685 us; speedup vs baseline: 1.1150x; 1.1150x over previous
//
#include <hip/hip_runtime.h>
#include <stdint.h>

// ColBERT MaxSim on MI355X (gfx950), round 13.
// scores[b,c] = sum_n max_s dot(qs[b,n,:], ps[c,s,:])
// qs: (64, 32, 128) f32, ps: (64, 1024, 128) f32, out: (64, 64) f32.
//
// R12 post-mortem: reg-transit staging (f32->cvt->ds_write) re-triggered qf
// demotion (VGPR 92 < qf64+acc32; FETCH 2x from per-tile global qf re-loads;
// maxsim 67 us). Locked-in lesson: the allocator demotes loop-invariant
// loaded values whenever inner-loop staging transients exist; ONLY the
// gload_lds path (zero staging VGPRs) keeps qf resident. So: cvt_kernel +
// g_bf + gload_lds staging (R11, proven maxsim <42, est ~38) is the base.
//
// R13 (one variable on R11): 64-token tiles instead of 32. Per-barrier work
// doubles (32 MFMA + 16 ds_read per wave), barrier count halves (32 -> 16),
// attacking the per-barrier vmcnt(0)+lgkm drain that accounts for most of
// the gap to the 13.7 us MFMA wall. LDS 2 x 16 KB = 32 KB (2 blocks/CU ok).
// The two 32-row sub-tiles reuse the same 2 acc chains, so register demand
// is unchanged from R11. Predict: maxsim stays out of top-5 (est 26-30 us),
// dur 111.5 -> ~99-103. If maxsim appears in top-5 (>42), revert to R11.
//
// Budget (all rounds reconciled): unconditional ws poison fill ~43 us +
// cvt ~8 + maxsim + inter-dispatch gaps ~22.

typedef __bf16 bf16x8 __attribute__((ext_vector_type(8)));
typedef float floatx16 __attribute__((ext_vector_type(16)));

#define QS_N (64u * 32u * 128u)    // 262144
#define PS_N (64u * 1024u * 128u)  // 8388608

// Static bf16 staging buffer: qs in [0, QS_N), ps in [QS_N, QS_N+PS_N).
__device__ ushort g_bf[QS_N + PS_N];

__global__ __launch_bounds__(256) void cvt_kernel(const float* __restrict__ qs,
                                                  const float* __restrict__ ps) {
  const int nq4 = QS_N / 4;
  const int n4 = (QS_N + PS_N) / 4;
  int i = blockIdx.x * 256 + threadIdx.x;
  if (i >= n4) return;
  float4 f = (i < nq4) ? ((const float4*)qs)[i] : ((const float4*)ps)[i - nq4];
  union { ushort4 s; struct { __bf16 a, b, c, d; } h; } o;
  o.h.a = (__bf16)f.x; o.h.b = (__bf16)f.y; o.h.c = (__bf16)f.z; o.h.d = (__bf16)f.w;
  ((ushort4*)g_bf)[i] = o.s;
}

__device__ inline float rmax16(const floatx16& a) {
  // Nested fmaxf triples fuse to v_max3_f32.
  float m0 = fmaxf(fmaxf(a[0], a[1]), fmaxf(a[2], a[3]));
  float m1 = fmaxf(fmaxf(a[4], a[5]), fmaxf(a[6], a[7]));
  float m2 = fmaxf(fmaxf(a[8], a[9]), fmaxf(a[10], a[11]));
  float m3 = fmaxf(fmaxf(a[12], a[13]), fmaxf(a[14], a[15]));
  return fmaxf(fmaxf(m0, m1), fmaxf(m2, m3));
}

// global_load_lds: builtin takes AS1/AS3 pointers; C-style casts addrspacecast.
typedef __attribute__((address_space(1))) const void gas_t;
typedef __attribute__((address_space(3))) void las_t;
__device__ inline void gload_lds16(const ushort* g, ushort* l) {
  __builtin_amdgcn_global_load_lds((gas_t*)g, (las_t*)l, 16, 0, 0);
}

#define ZERO16 {0, 0, 0, 0, 0, 0, 0, 0, 0, 0, 0, 0, 0, 0, 0, 0}

__global__ __launch_bounds__(256) void maxsim_kernel(float* __restrict__ out) {
  const ushort* qsb = g_bf;
  const ushort* psb = g_bf + QS_N;

  const int lane = threadIdx.x & 63;
  const int wave = threadIdx.x >> 6;

  // XCD swizzle: the 8 blocks of doc c all land on XCD c>>3 -> P_c (256 KB
  // bf16) L2-resident after the first reader.
  const int xcd = blockIdx.x & 7;
  const int slot = blockIdx.x >> 3;   // 0..63
  const int c = xcd * 8 + (slot >> 3);
  const int bg = slot & 7;
  const int qb0 = bg * 8 + wave * 2;  // this wave's first query (of 2)

  const int row = lane & 31;          // A-frag: s-row; B-frag: query token n
  const int hi8 = (lane >> 5) * 8;    // K-half selector (elements)

  // Q B-frags straight global->reg (L2/L3-hot, 16B loads), resident all
  // kernel (64 VGPRs): qf[bb][k] = Q[qb0+bb][n=row][k*16 + hi8 + 0..7].
  bf16x8 qf[2][8];
#pragma unroll
  for (int bb = 0; bb < 2; ++bb) {
    const ushort* q = qsb + ((qb0 + bb) * 32 + row) * 128 + hi8;
#pragma unroll
    for (int k = 0; k < 8; ++k)
      qf[bb][k] = *(const bf16x8*)(q + k * 16);
  }

  // P tile double-buffer, 64 tokens/tile = 16 KiB each, A-frag order:
  // sub-tile u (32 rows) at u*8192 B, chunk j (=k) at j*1024 B, lane at 16 B.
  __shared__ __align__(16) ushort lds_p[2][8192];

  // Per-lane global element offset (add s-offset*128 + j*16 per chunk).
  const int pg_lane = (c * 1024 + row) * 128 + hi8;

  // Prologue: stage tile 0 (wave w issues global chunks m = 4w..4w+3;
  // m -> sub-tile u = m>>3, chunk j = m&7).
#pragma unroll
  for (int jj = 0; jj < 4; ++jj) {
    const int m = wave * 4 + jj;
    const int u = m >> 3, j = m & 7;
    gload_lds16(psb + pg_lane + u * 32 * 128 + j * 16,
                &lds_p[0][u * 4096 + j * 512]);
  }
  __syncthreads();

  float vmax0 = -3.4e38f, vmax1 = -3.4e38f;
  int cb = 0;

#pragma unroll 1
  for (int t = 0; t < 16; ++t) {
    // Stage tile t+1 into the back buffer; the ~500 cyc latency hides under
    // this tile's 32 MFMAs.
    if (t < 15) {
      const int soff = (t + 1) * 64 * 128;
#pragma unroll
      for (int jj = 0; jj < 4; ++jj) {
        const int m = wave * 4 + jj;
        const int u = m >> 3, j = m & 7;
        gload_lds16(psb + pg_lane + soff + u * 32 * 128 + j * 16,
                    &lds_p[cb ^ 1][u * 4096 + j * 512]);
      }
    }
    // Compute tile t: two 32-row sub-tiles, same 2 acc chains reused.
    const ushort* lp = &lds_p[cb][0] + lane * 8;
#pragma unroll
    for (int u = 0; u < 2; ++u) {
      floatx16 acc0 = ZERO16, acc1 = ZERO16;
#pragma unroll
      for (int k = 0; k < 8; ++k) {
        bf16x8 af = *(const bf16x8*)(lp + u * 4096 + k * 512);
        acc0 = __builtin_amdgcn_mfma_f32_32x32x16_bf16(af, qf[0][k], acc0, 0, 0, 0);
        acc1 = __builtin_amdgcn_mfma_f32_32x32x16_bf16(af, qf[1][k], acc1, 0, 0, 0);
      }
      vmax0 = fmaxf(vmax0, rmax16(acc0));
      vmax1 = fmaxf(vmax1, rmax16(acc1));
    }
    // Barrier: staging of t+1 landed AND all readers of cb are done.
    __syncthreads();
    cb ^= 1;
  }

  // acc D-layout: col = lane&31 = token n; lanes l, l^32 hold complementary
  // row-halves -> max-merge, then butterfly-sum the 32 tokens.
  vmax0 = fmaxf(vmax0, __shfl_xor(vmax0, 32, 64));
  vmax1 = fmaxf(vmax1, __shfl_xor(vmax1, 32, 64));
#pragma unroll
  for (int o = 16; o > 0; o >>= 1) {
    vmax0 += __shfl_xor(vmax0, o, 64);
    vmax1 += __shfl_xor(vmax1, o, 64);
  }
  if (lane == 0) {
    out[(qb0 + 0) * 64 + c] = vmax0;
    out[(qb0 + 1) * 64 + c] = vmax1;
  }
}

extern "C" void kernel_launch(void* const* d_in, const int* in_sizes, int n_in,
                              void* d_out, int out_size, void* d_ws, size_t ws_size,
                              hipStream_t stream) {
  const float* qs = (const float*)d_in[0];
  const float* ps = (const float*)d_in[1];
  float* out = (float*)d_out;
  (void)d_ws; (void)ws_size;  // ws poison fill is unconditional; ws gives us nothing

  const int n4 = (int)((QS_N + PS_N) / 4);
  cvt_kernel<<<(n4 + 255) / 256, 256, 0, stream>>>(qs, ps);
  maxsim_kernel<<<dim3(512), dim3(256), 0, stream>>>(out);
}